// Round 8
// baseline (552.938 us; speedup 1.0000x reference)
//
#include <hip/hip_runtime.h>

// ---------- types / helpers ----------
typedef __bf16 bf16x8 __attribute__((ext_vector_type(8)));
typedef unsigned short u16x8 __attribute__((ext_vector_type(8)));
typedef float f32x4 __attribute__((ext_vector_type(4)));

union BU {
    u16x8 u;
    bf16x8 b;
};

static __device__ __forceinline__ float b2f(unsigned short u) {
    return __uint_as_float(((unsigned)u) << 16);
}
static __device__ __forceinline__ unsigned short f2b(float f) {
    unsigned u = __float_as_uint(f);
    unsigned r = (u + 0x7FFF + ((u >> 16) & 1)) >> 16;  // RNE
    return (unsigned short)r;
}

// ---------- weight split+transpose + bcat ----------
__global__ __launch_bounds__(256) void wsplit_kernel(
    const float* __restrict__ W1, const float* __restrict__ W2, const float* __restrict__ W3,
    const float* __restrict__ Wp1, const float* __restrict__ Wt1,
    unsigned short* __restrict__ W1hi, unsigned short* __restrict__ W1lo,
    unsigned short* __restrict__ W2hi, unsigned short* __restrict__ W2lo,
    unsigned short* __restrict__ W3hi, unsigned short* __restrict__ W3lo,
    unsigned short* __restrict__ Wchi, unsigned short* __restrict__ Wclo,
    const float* __restrict__ bp1, const float* __restrict__ bt1, float* __restrict__ bcat) {
    int b = blockIdx.x;
    int tid = threadIdx.x;
    if (b < 288) {
        const float* W;
        unsigned short *Whi, *Wlo;
        int lb, ncshift, total;
        if (b < 64)       { W = W1;  Whi = W1hi; Wlo = W1lo; lb = b;       ncshift = 7; total = 16384; }
        else if (b < 128) { W = W2;  Whi = W2hi; Wlo = W2lo; lb = b - 64;  ncshift = 7; total = 16384; }
        else if (b < 192) { W = W3;  Whi = W3hi; Wlo = W3lo; lb = b - 128; ncshift = 7; total = 16384; }
        else if (b < 256) { W = Wp1; Whi = Wchi; Wlo = Wclo; lb = b - 192; ncshift = 7; total = 16384; }
        else              { W = Wt1; Whi = Wchi + 128 * 128; Wlo = Wclo + 128 * 128; lb = b - 256; ncshift = 6; total = 8192; }
        int idx = lb * 256 + tid;
        if (idx < total) {
            int k = idx >> ncshift;
            int n = idx - (k << ncshift);
            float a = W[idx];
            unsigned short hb = f2b(a);
            Whi[(n << 7) + k] = hb;
            Wlo[(n << 7) + k] = f2b(a - b2f(hb));
        }
        return;
    }
    if (tid < 128) bcat[tid] = bp1[tid];
    else if (tid < 192) bcat[tid] = bt1[tid - 128];
}

// ---------- split 8 f32 -> hi/lo bf16x8 ----------
static __device__ __forceinline__ void split8(const float4 a01, const float4 a23,
                                              bf16x8& hi, bf16x8& lo) {
    float a[8] = {a01.x, a01.y, a01.z, a01.w, a23.x, a23.y, a23.z, a23.w};
    BU h, l;
#pragma unroll
    for (int j = 0; j < 8; ++j) {
        unsigned short hb = f2b(a[j]);
        h.u[j] = hb;
        l.u[j] = f2b(a[j] - b2f(hb));
    }
    hi = h.b;
    lo = l.b;
}

// ---------- GEMM accumulate: f32 A (3-MFMA split) ----------
template <int NT>
static __device__ __forceinline__ void gemm_acc_f32(const float* __restrict__ A,
                                                    const unsigned short* __restrict__ Whi,
                                                    const unsigned short* __restrict__ Wlo,
                                                    int arow, int m16, int quad, f32x4* acc) {
    const float* Arow = A + (size_t)arow * 128 + quad * 8;
#pragma unroll
    for (int kb = 0; kb < 4; ++kb) {
        float4 a01 = *reinterpret_cast<const float4*>(Arow + kb * 32);
        float4 a23 = *reinterpret_cast<const float4*>(Arow + kb * 32 + 4);
        bf16x8 ahi, alo;
        split8(a01, a23, ahi, alo);
#pragma unroll
        for (int t = 0; t < NT; ++t) {
            size_t woff = (size_t)(t * 16 + m16) * 128 + quad * 8 + kb * 32;
            BU bh, bl;
            bh.u = *reinterpret_cast<const u16x8*>(Whi + woff);
            bl.u = *reinterpret_cast<const u16x8*>(Wlo + woff);
            acc[t] = __builtin_amdgcn_mfma_f32_16x16x32_bf16(ahi, bh.b, acc[t], 0, 0, 0);
            acc[t] = __builtin_amdgcn_mfma_f32_16x16x32_bf16(ahi, bl.b, acc[t], 0, 0, 0);
            acc[t] = __builtin_amdgcn_mfma_f32_16x16x32_bf16(alo, bh.b, acc[t], 0, 0, 0);
        }
    }
}

// epilogue: plain bf16 store
template <int NT>
static __device__ __forceinline__ void gemm_store_plain(unsigned short* __restrict__ C,
                                                        int row_base, int m16, int quad,
                                                        f32x4* acc, int nrows) {
#pragma unroll
    for (int t = 0; t < NT; ++t) {
#pragma unroll
        for (int r = 0; r < 4; ++r) {
            int row = row_base + quad * 4 + r;
            if (row < nrows)
                C[(size_t)row * (NT * 16) + t * 16 + m16] = f2b(acc[t][r]);
        }
    }
}

// ---------- fused: merged deg+fill edge pass || layer-1 GEMM (f32 A, unscaled) ----------
// 512-thread blocks. Same 1:2 interleave: gemm blocks = 8 waves x 16 rows = 128
// rows; edge blocks = 4096 edges. [R7: time-neutral vs 256t; kept for fewer blocks]
__global__ __launch_bounds__(512) void fg2_kernel(const float* __restrict__ A,
                                                  const unsigned short* __restrict__ Whi,
                                                  const unsigned short* __restrict__ Wlo,
                                                  unsigned short* __restrict__ C, int nrows,
                                                  int fbn,
                                                  const int* __restrict__ ei,
                                                  int* __restrict__ deg,
                                                  int* __restrict__ slots, int E) {
    const int bid = blockIdx.x;
    const int tid = threadIdx.x;
    const int trip = bid / 3, r = bid % 3;
    if (r == 1 && trip < fbn) {  // edge block: deg+fill merged, 8 edges/thread
        int base = (trip * 512 + tid) * 8;
        int dsts[8], srcs[8], ps[8];
#pragma unroll
        for (int k = 0; k < 8; ++k) {
            int e = base + k;
            dsts[k] = (e < E) ? ei[E + e] : -1;
            srcs[k] = (e < E) ? ei[e] : 0;
        }
#pragma unroll
        for (int k = 0; k < 8; ++k)
            if (dsts[k] >= 0) ps[k] = atomicAdd(&deg[dsts[k]], 1);
#pragma unroll
        for (int k = 0; k < 8; ++k)
            if (dsts[k] >= 0 && ps[k] < 64)  // cap 64 (P(deg>64) ~ 1e-24)
                __builtin_nontemporal_store(srcs[k], &slots[(size_t)dsts[k] * 64 + ps[k]]);
    } else {  // gemm block: 128 rows
        int gid = bid - min(trip, fbn) - ((r > 1 && trip < fbn) ? 1 : 0);
        const int wave = tid >> 6, lane = tid & 63;
        const int m16 = lane & 15, quad = lane >> 4;
        const int row_base = gid * 128 + wave * 16;
        int arow = row_base + m16;
        if (arow >= nrows) arow = nrows - 1;
        f32x4 acc[8] = {};
        gemm_acc_f32<8>(A, Whi, Wlo, arow, m16, quad, acc);
        gemm_store_plain<8>(C, row_base, m16, quad, acc, nrows);
    }
}

// ---------- pull 4 nodes (one wave) into rows [wave*4 .. wave*4+3] of the
// block's 32x128 swizzled LDS tile ----------
// EXACT R2/R5 inner loop when SRCSCALED=true (proven best codegen). When
// SRCSCALED=false [R8], the source rows are UNSCALED (raw x@W1): each gathered
// row is multiplied by rsqrt(deg[src]+1) on the fly (deg is 400KB, L2-resident;
// the 4 deg loads/round co-issue with the 4 row loads and hide under them).
// This replaces the separate scale_kernel pass (~51MB round-trip + launch gap),
// and drops one bf16 rounding step (scale applied in f32).
// R8 gather form: lane = slot(0..3)*16 + chunk(0..15); per round slot s gathers
// 16B chunk of edge r*4+s. Row i stored at elem (chunk*8) ^ ((i&7)<<3)
// (byte ^ ((row&7)<<4)) so the MFMA-phase ds_read_b128 is bank-uniform.
template <bool SRCSCALED>
static __device__ __forceinline__ void pull4_to_lds(const unsigned short* __restrict__ hs,
                                                    const int* __restrict__ slots,
                                                    const int* __restrict__ deg,
                                                    const float* __restrict__ bias,
                                                    unsigned short* __restrict__ ldsw,
                                                    int row_base, int wave, int lane, int n) {
    const int slot = lane >> 4, chunk = lane & 15;
    // prefetch setup for all 4 nodes (pipelines the deg/slots latencies)
    int dgs[4], idxs[4];
#pragma unroll
    for (int i = 0; i < 4; ++i) {
        int node = row_base + wave * 4 + i;
        dgs[i] = (node < n) ? deg[node] : 0;
    }
#pragma unroll
    for (int i = 0; i < 4; ++i) {
        int node = row_base + wave * 4 + i;
        // lane-masked: only lanes < deg load a slot entry (saves 3/4 of lines at deg~16)
        idxs[i] = (node < n && lane < min(dgs[i], 64)) ? slots[(size_t)node * 64 + lane] : 0;
    }
#pragma unroll
    for (int i = 0; i < 4; ++i) {
        const int node = row_base + wave * 4 + i;
        if (node >= n) continue;  // wave-uniform
        const int tr = wave * 4 + i;  // tile row
        const float d = rsqrtf((float)dgs[i] + 1.0f);
        const int m = min(dgs[i], 64);
        const int myidx = idxs[i];

        BU sv;
        sv.u = *reinterpret_cast<const u16x8*>(hs + (size_t)node * 128 + chunk * 8);

        float acc[8] = {};
        const int rounds = (m + 3) >> 2;
        int r = 0;
        for (; r + 4 <= rounds; r += 4) {
            int e0 = r * 4 + slot, e1 = e0 + 4, e2 = e0 + 8, e3 = e0 + 12;
            int s0 = __shfl(myidx, e0), s1 = __shfl(myidx, e1);
            int s2 = __shfl(myidx, e2), s3 = __shfl(myidx, e3);
            s0 = (unsigned)s0 < (unsigned)n ? s0 : 0;  // defensive (masked lanes hold 0)
            s1 = (unsigned)s1 < (unsigned)n ? s1 : 0;
            s2 = (unsigned)s2 < (unsigned)n ? s2 : 0;
            s3 = (unsigned)s3 < (unsigned)n ? s3 : 0;
            bool ok0 = e0 < m, ok1 = e1 < m, ok2 = e2 < m, ok3 = e3 < m;
            // co-issue deg loads (L2-hit) ahead of the row loads so both overlap
            int dv0 = 0, dv1 = 0, dv2 = 0, dv3 = 0;
            if (!SRCSCALED) {
                if (ok0) dv0 = deg[s0];
                if (ok1) dv1 = deg[s1];
                if (ok2) dv2 = deg[s2];
                if (ok3) dv3 = deg[s3];
            }
            BU h0, h1, h2, h3;
            if (ok0) h0.u = *reinterpret_cast<const u16x8*>(hs + (size_t)s0 * 128 + chunk * 8);
            if (ok1) h1.u = *reinterpret_cast<const u16x8*>(hs + (size_t)s1 * 128 + chunk * 8);
            if (ok2) h2.u = *reinterpret_cast<const u16x8*>(hs + (size_t)s2 * 128 + chunk * 8);
            if (ok3) h3.u = *reinterpret_cast<const u16x8*>(hs + (size_t)s3 * 128 + chunk * 8);
            if (ok0) {
                float w = SRCSCALED ? 1.0f : rsqrtf((float)dv0 + 1.0f);
#pragma unroll
                for (int j = 0; j < 8; ++j)
                    acc[j] += SRCSCALED ? b2f(h0.u[j]) : w * b2f(h0.u[j]);
            }
            if (ok1) {
                float w = SRCSCALED ? 1.0f : rsqrtf((float)dv1 + 1.0f);
#pragma unroll
                for (int j = 0; j < 8; ++j)
                    acc[j] += SRCSCALED ? b2f(h1.u[j]) : w * b2f(h1.u[j]);
            }
            if (ok2) {
                float w = SRCSCALED ? 1.0f : rsqrtf((float)dv2 + 1.0f);
#pragma unroll
                for (int j = 0; j < 8; ++j)
                    acc[j] += SRCSCALED ? b2f(h2.u[j]) : w * b2f(h2.u[j]);
            }
            if (ok3) {
                float w = SRCSCALED ? 1.0f : rsqrtf((float)dv3 + 1.0f);
#pragma unroll
                for (int j = 0; j < 8; ++j)
                    acc[j] += SRCSCALED ? b2f(h3.u[j]) : w * b2f(h3.u[j]);
            }
        }
        for (; r < rounds; ++r) {
            int e0 = r * 4 + slot;
            int s0 = __shfl(myidx, e0);
            s0 = (unsigned)s0 < (unsigned)n ? s0 : 0;
            if (e0 < m) {
                int dv0 = SRCSCALED ? 0 : deg[s0];
                BU h0;
                h0.u = *reinterpret_cast<const u16x8*>(hs + (size_t)s0 * 128 + chunk * 8);
                float w = SRCSCALED ? 1.0f : rsqrtf((float)dv0 + 1.0f);
#pragma unroll
                for (int j = 0; j < 8; ++j)
                    acc[j] += SRCSCALED ? b2f(h0.u[j]) : w * b2f(h0.u[j]);
            }
        }
        // reduce across the 4 slots (lane bits 4,5)
#pragma unroll
        for (int j = 0; j < 8; ++j) {
            acc[j] += __shfl_xor(acc[j], 16);
            acc[j] += __shfl_xor(acc[j], 32);
        }
        if (slot == 0) {
            const float selfw = SRCSCALED ? 1.0f : d;  // self row needs dinv(node) too
            BU o;
#pragma unroll
            for (int j = 0; j < 8; ++j)
                o.u[j] = f2b(fmaxf((acc[j] + selfw * b2f(sv.u[j])) * d + bias[chunk * 8 + j], 0.f));
            *reinterpret_cast<u16x8*>(&ldsw[tr * 128 + ((chunk * 8) ^ ((tr & 7) << 3))]) = o.u;
        }
    }
}

// ---------- fused pull + GEMM (layers 2,3), 32-row tile, 512-thread blocks ----------
// 8 waves each pull 4 nodes, then each wave computes its 16 output cols for BOTH
// 16-row halves of the 32x128 @ 128x128 product (weights loaded once, used twice).
template <bool SRCSCALED>
__global__ __launch_bounds__(512) void pg_kernel(const unsigned short* __restrict__ hs,
                                                 const int* __restrict__ slots,
                                                 const int* __restrict__ deg,
                                                 const float* __restrict__ bias,
                                                 const unsigned short* __restrict__ Whi,
                                                 const unsigned short* __restrict__ Wlo,
                                                 unsigned short* __restrict__ C, int n) {
    __shared__ unsigned short lds[32 * 128];  // 8 KiB swizzled tile
    const int tid = threadIdx.x;
    const int wave = tid >> 6, lane = tid & 63;
    const int row_base = blockIdx.x * 32;
    pull4_to_lds<SRCSCALED>(hs, slots, deg, bias, lds, row_base, wave, lane, n);
    __syncthreads();
    const int m16 = lane & 15, quad = lane >> 4;
    f32x4 acc0 = {}, acc1 = {};
#pragma unroll
    for (int kb = 0; kb < 4; ++kb) {
        const int aoff = (quad * 8 + kb * 32) ^ ((m16 & 7) << 3);  // (16+m16)&7 == m16&7
        BU a0, a1;
        a0.u = *reinterpret_cast<const u16x8*>(&lds[m16 * 128 + aoff]);
        a1.u = *reinterpret_cast<const u16x8*>(&lds[(16 + m16) * 128 + aoff]);
        int col = wave * 16 + m16;
        size_t woff = (size_t)col * 128 + quad * 8 + kb * 32;
        BU bh, bl;
        bh.u = *reinterpret_cast<const u16x8*>(Whi + woff);
        bl.u = *reinterpret_cast<const u16x8*>(Wlo + woff);
        acc0 = __builtin_amdgcn_mfma_f32_16x16x32_bf16(a0.b, bh.b, acc0, 0, 0, 0);
        acc0 = __builtin_amdgcn_mfma_f32_16x16x32_bf16(a0.b, bl.b, acc0, 0, 0, 0);
        acc1 = __builtin_amdgcn_mfma_f32_16x16x32_bf16(a1.b, bh.b, acc1, 0, 0, 0);
        acc1 = __builtin_amdgcn_mfma_f32_16x16x32_bf16(a1.b, bl.b, acc1, 0, 0, 0);
    }
#pragma unroll
    for (int r = 0; r < 4; ++r) {
        int row0 = row_base + quad * 4 + r;
        int row1 = row_base + 16 + quad * 4 + r;
        if (row0 < n) {
            float d = rsqrtf((float)deg[row0] + 1.0f);
            C[(size_t)row0 * 128 + wave * 16 + m16] = f2b(acc0[r] * d);
        }
        if (row1 < n) {
            float d = rsqrtf((float)deg[row1] + 1.0f);
            C[(size_t)row1 * 128 + wave * 16 + m16] = f2b(acc1[r] * d);
        }
    }
}

// ---------- fused pull + heads GEMM (12 col-tiles over 8 waves) + reduce -> out[N,3] ----------
// 32-row tile. Every wave computes pos-head tile 'wave' (cols wave*16..+15) for
// both row halves; waves 0-3 additionally compute the time-head tile
// (cols 128+wave*16..) for both halves.
__global__ __launch_bounds__(512) void pg_heads_kernel(
    const unsigned short* __restrict__ hs, const int* __restrict__ slots,
    const int* __restrict__ deg, const float* __restrict__ bias,
    const unsigned short* __restrict__ Whi, const unsigned short* __restrict__ Wlo,
    const float* __restrict__ bcat, const float* __restrict__ Wp2,
    const float* __restrict__ bp2, const float* __restrict__ Wt2,
    const float* __restrict__ bt2, float* __restrict__ out, int n) {
    __shared__ unsigned short lds[32 * 128];
    __shared__ float part[8][32][3];
    const int tid = threadIdx.x;
    const int wave = tid >> 6, lane = tid & 63;
    const int row_base = blockIdx.x * 32;
    pull4_to_lds<true>(hs, slots, deg, bias, lds, row_base, wave, lane, n);
    __syncthreads();
    const int m16 = lane & 15, quad = lane >> 4;
    f32x4 acc0a = {}, acc0b = {}, acc1a = {}, acc1b = {};
#pragma unroll
    for (int kb = 0; kb < 4; ++kb) {
        const int aoff = (quad * 8 + kb * 32) ^ ((m16 & 7) << 3);
        BU a0, a1;
        a0.u = *reinterpret_cast<const u16x8*>(&lds[m16 * 128 + aoff]);
        a1.u = *reinterpret_cast<const u16x8*>(&lds[(16 + m16) * 128 + aoff]);
        {
            int col = wave * 16 + m16;
            size_t woff = (size_t)col * 128 + quad * 8 + kb * 32;
            BU bh, bl;
            bh.u = *reinterpret_cast<const u16x8*>(Whi + woff);
            bl.u = *reinterpret_cast<const u16x8*>(Wlo + woff);
            acc0a = __builtin_amdgcn_mfma_f32_16x16x32_bf16(a0.b, bh.b, acc0a, 0, 0, 0);
            acc0a = __builtin_amdgcn_mfma_f32_16x16x32_bf16(a0.b, bl.b, acc0a, 0, 0, 0);
            acc0b = __builtin_amdgcn_mfma_f32_16x16x32_bf16(a1.b, bh.b, acc0b, 0, 0, 0);
            acc0b = __builtin_amdgcn_mfma_f32_16x16x32_bf16(a1.b, bl.b, acc0b, 0, 0, 0);
        }
        if (wave < 4) {
            int col = 128 + wave * 16 + m16;
            size_t woff = (size_t)col * 128 + quad * 8 + kb * 32;
            BU bh, bl;
            bh.u = *reinterpret_cast<const u16x8*>(Whi + woff);
            bl.u = *reinterpret_cast<const u16x8*>(Wlo + woff);
            acc1a = __builtin_amdgcn_mfma_f32_16x16x32_bf16(a0.b, bh.b, acc1a, 0, 0, 0);
            acc1a = __builtin_amdgcn_mfma_f32_16x16x32_bf16(a0.b, bl.b, acc1a, 0, 0, 0);
            acc1b = __builtin_amdgcn_mfma_f32_16x16x32_bf16(a1.b, bh.b, acc1b, 0, 0, 0);
            acc1b = __builtin_amdgcn_mfma_f32_16x16x32_bf16(a1.b, bl.b, acc1b, 0, 0, 0);
        }
    }
    // per-wave partial head reduction over its col tiles (both row halves)
#pragma unroll
    for (int r = 0; r < 4; ++r) {
        float p0a, p1a, tta = 0.f, p0b, p1b, ttb = 0.f;
        {
            int c = wave * 16 + m16;  // pos-head col (<128)
            float w0 = Wp2[c * 2 + 0], w1 = Wp2[c * 2 + 1], bc = bcat[c];
            float va = fmaxf(acc0a[r] + bc, 0.f);
            float vb = fmaxf(acc0b[r] + bc, 0.f);
            p0a = va * w0; p1a = va * w1;
            p0b = vb * w0; p1b = vb * w1;
        }
        if (wave < 4) {
            int c = 128 + wave * 16 + m16;  // time-head col
            float wt = Wt2[c - 128], bc = bcat[c];
            tta = fmaxf(acc1a[r] + bc, 0.f) * wt;
            ttb = fmaxf(acc1b[r] + bc, 0.f) * wt;
        }
#pragma unroll
        for (int mask = 1; mask < 16; mask <<= 1) {
            p0a += __shfl_xor(p0a, mask);
            p1a += __shfl_xor(p1a, mask);
            tta += __shfl_xor(tta, mask);
            p0b += __shfl_xor(p0b, mask);
            p1b += __shfl_xor(p1b, mask);
            ttb += __shfl_xor(ttb, mask);
        }
        if (m16 == 0) {
            int trow = quad * 4 + r;
            part[wave][trow][0] = p0a;
            part[wave][trow][1] = p1a;
            part[wave][trow][2] = tta;
            part[wave][16 + trow][0] = p0b;
            part[wave][16 + trow][1] = p1b;
            part[wave][16 + trow][2] = ttb;
        }
    }
    __syncthreads();
    if (tid < 96) {
        int trow = tid / 3, c = tid - trow * 3;
        float s = 0.f;
#pragma unroll
        for (int w = 0; w < 8; ++w) s += part[w][trow][c];
        int row = row_base + trow;
        if (row < n) {
            float b = (c == 0) ? bp2[0] : (c == 1) ? bp2[1] : bt2[0];
            out[(size_t)row * 3 + c] = s + b;
        }
    }
}

// ---------- launcher ----------
extern "C" void kernel_launch(void* const* d_in, const int* in_sizes, int n_in,
                              void* d_out, int out_size, void* d_ws, size_t ws_size,
                              hipStream_t stream) {
    const int N = in_sizes[0] / 128;
    const int E = in_sizes[1] / 2;

    const float* x   = (const float*)d_in[0];
    const int* ei    = (const int*)d_in[1];
    const float* W1  = (const float*)d_in[2];
    const float* b1  = (const float*)d_in[3];
    const float* W2  = (const float*)d_in[4];
    const float* b2  = (const float*)d_in[5];
    const float* W3  = (const float*)d_in[6];
    const float* b3  = (const float*)d_in[7];
    const float* Wp1 = (const float*)d_in[8];
    const float* bp1 = (const float*)d_in[9];
    const float* Wp2 = (const float*)d_in[10];
    const float* bp2 = (const float*)d_in[11];
    const float* Wt1 = (const float*)d_in[12];
    const float* bt1 = (const float*)d_in[13];
    const float* Wt2 = (const float*)d_in[14];
    const float* bt2 = (const float*)d_in[15];
    float* out = (float*)d_out;

    char* ws = (char*)d_ws;
    size_t off = 0;
    auto alloc = [&](size_t bytes) {
        void* p = ws + off;
        off += (bytes + 255) & ~(size_t)255;
        return p;
    };
    int* deg        = (int*)alloc((size_t)N * 4);
    int* slots      = (int*)alloc((size_t)N * 64 * 4);
    unsigned short* W1hi = (unsigned short*)alloc(16384 * 2);
    unsigned short* W1lo = (unsigned short*)alloc(16384 * 2);
    unsigned short* W2hi = (unsigned short*)alloc(16384 * 2);
    unsigned short* W2lo = (unsigned short*)alloc(16384 * 2);
    unsigned short* W3hi = (unsigned short*)alloc(16384 * 2);
    unsigned short* W3lo = (unsigned short*)alloc(16384 * 2);
    unsigned short* Wchi = (unsigned short*)alloc(192 * 128 * 2);
    unsigned short* Wclo = (unsigned short*)alloc(192 * 128 * 2);
    float* bcat          = (float*)alloc(192 * 4);
    unsigned short* hsA  = (unsigned short*)alloc((size_t)N * 128 * 2);
    unsigned short* hsB  = (unsigned short*)alloc((size_t)N * 128 * 2);

    hipMemsetAsync(deg, 0, (size_t)N * 4, stream);

    // weight split + bcat (must finish before fg2's gemm reads W1hi/lo)
    wsplit_kernel<<<289, 256, 0, stream>>>(W1, W2, W3, Wp1, Wt1,
                                           W1hi, W1lo, W2hi, W2lo, W3hi, W3lo,
                                           Wchi, Wclo, bp1, bt1, bcat);

    const int gb128 = (N + 127) / 128;
    const int gb32 = (N + 31) / 32;
    const int fbn = ((E + 7) / 8 + 511) / 512;

    // edge pass (deg+fill merged) || layer-1 GEMM (unscaled), 1:2 interleave
    fg2_kernel<<<gb128 + fbn, 512, 0, stream>>>(x, W1hi, W1lo, hsA, N, fbn, ei, deg, slots, E);

    // layer 2: gather UNSCALED hsA with on-the-fly dinv(src) -> @W2 -> pre-scaled hsB
    // (replaces the separate scale_kernel pass — R8)
    pg_kernel<false><<<gb32, 512, 0, stream>>>(hsA, slots, deg, b1, W2hi, W2lo, hsB, N);
    // layer 3: gather pre-scaled hsB -> @W3 -> pre-scaled hsA
    pg_kernel<true><<<gb32, 512, 0, stream>>>(hsB, slots, deg, b2, W3hi, W3lo, hsA, N);
    // heads: gather pre-scaled hsA -> @[Wp1|Wt1] -> fused head reduce -> out
    pg_heads_kernel<<<gb32, 512, 0, stream>>>(hsA, slots, deg, b3, Wchi, Wclo,
                                              bcat, Wp2, bp2, Wt2, bt2, out, N);
}

// Round 9
// 538.257 us; speedup vs baseline: 1.0273x; 1.0273x over previous
//
#include <hip/hip_runtime.h>

// ---------- types / helpers ----------
typedef __bf16 bf16x8 __attribute__((ext_vector_type(8)));
typedef unsigned short u16x8 __attribute__((ext_vector_type(8)));
typedef float f32x4 __attribute__((ext_vector_type(4)));

union BU {
    u16x8 u;
    bf16x8 b;
};

static __device__ __forceinline__ float b2f(unsigned short u) {
    return __uint_as_float(((unsigned)u) << 16);
}
static __device__ __forceinline__ unsigned short f2b(float f) {
    unsigned u = __float_as_uint(f);
    unsigned r = (u + 0x7FFF + ((u >> 16) & 1)) >> 16;  // RNE
    return (unsigned short)r;
}

// ---------- weight split+transpose + bcat ----------
__global__ __launch_bounds__(256) void wsplit_kernel(
    const float* __restrict__ W1, const float* __restrict__ W2, const float* __restrict__ W3,
    const float* __restrict__ Wp1, const float* __restrict__ Wt1,
    unsigned short* __restrict__ W1hi, unsigned short* __restrict__ W1lo,
    unsigned short* __restrict__ W2hi, unsigned short* __restrict__ W2lo,
    unsigned short* __restrict__ W3hi, unsigned short* __restrict__ W3lo,
    unsigned short* __restrict__ Wchi, unsigned short* __restrict__ Wclo,
    const float* __restrict__ bp1, const float* __restrict__ bt1, float* __restrict__ bcat) {
    int b = blockIdx.x;
    int tid = threadIdx.x;
    if (b < 288) {
        const float* W;
        unsigned short *Whi, *Wlo;
        int lb, ncshift, total;
        if (b < 64)       { W = W1;  Whi = W1hi; Wlo = W1lo; lb = b;       ncshift = 7; total = 16384; }
        else if (b < 128) { W = W2;  Whi = W2hi; Wlo = W2lo; lb = b - 64;  ncshift = 7; total = 16384; }
        else if (b < 192) { W = W3;  Whi = W3hi; Wlo = W3lo; lb = b - 128; ncshift = 7; total = 16384; }
        else if (b < 256) { W = Wp1; Whi = Wchi; Wlo = Wclo; lb = b - 192; ncshift = 7; total = 16384; }
        else              { W = Wt1; Whi = Wchi + 128 * 128; Wlo = Wclo + 128 * 128; lb = b - 256; ncshift = 6; total = 8192; }
        int idx = lb * 256 + tid;
        if (idx < total) {
            int k = idx >> ncshift;
            int n = idx - (k << ncshift);
            float a = W[idx];
            unsigned short hb = f2b(a);
            Whi[(n << 7) + k] = hb;
            Wlo[(n << 7) + k] = f2b(a - b2f(hb));
        }
        return;
    }
    if (tid < 128) bcat[tid] = bp1[tid];
    else if (tid < 192) bcat[tid] = bt1[tid - 128];
}

// ---------- split 8 f32 -> hi/lo bf16x8 ----------
static __device__ __forceinline__ void split8(const float4 a01, const float4 a23,
                                              bf16x8& hi, bf16x8& lo) {
    float a[8] = {a01.x, a01.y, a01.z, a01.w, a23.x, a23.y, a23.z, a23.w};
    BU h, l;
#pragma unroll
    for (int j = 0; j < 8; ++j) {
        unsigned short hb = f2b(a[j]);
        h.u[j] = hb;
        l.u[j] = f2b(a[j] - b2f(hb));
    }
    hi = h.b;
    lo = l.b;
}

// ---------- GEMM accumulate: f32 A (3-MFMA split) ----------
template <int NT>
static __device__ __forceinline__ void gemm_acc_f32(const float* __restrict__ A,
                                                    const unsigned short* __restrict__ Whi,
                                                    const unsigned short* __restrict__ Wlo,
                                                    int arow, int m16, int quad, f32x4* acc) {
    const float* Arow = A + (size_t)arow * 128 + quad * 8;
#pragma unroll
    for (int kb = 0; kb < 4; ++kb) {
        float4 a01 = *reinterpret_cast<const float4*>(Arow + kb * 32);
        float4 a23 = *reinterpret_cast<const float4*>(Arow + kb * 32 + 4);
        bf16x8 ahi, alo;
        split8(a01, a23, ahi, alo);
#pragma unroll
        for (int t = 0; t < NT; ++t) {
            size_t woff = (size_t)(t * 16 + m16) * 128 + quad * 8 + kb * 32;
            BU bh, bl;
            bh.u = *reinterpret_cast<const u16x8*>(Whi + woff);
            bl.u = *reinterpret_cast<const u16x8*>(Wlo + woff);
            acc[t] = __builtin_amdgcn_mfma_f32_16x16x32_bf16(ahi, bh.b, acc[t], 0, 0, 0);
            acc[t] = __builtin_amdgcn_mfma_f32_16x16x32_bf16(ahi, bl.b, acc[t], 0, 0, 0);
            acc[t] = __builtin_amdgcn_mfma_f32_16x16x32_bf16(alo, bh.b, acc[t], 0, 0, 0);
        }
    }
}

// epilogue: plain bf16 store
template <int NT>
static __device__ __forceinline__ void gemm_store_plain(unsigned short* __restrict__ C,
                                                        int row_base, int m16, int quad,
                                                        f32x4* acc, int nrows) {
#pragma unroll
    for (int t = 0; t < NT; ++t) {
#pragma unroll
        for (int r = 0; r < 4; ++r) {
            int row = row_base + quad * 4 + r;
            if (row < nrows)
                C[(size_t)row * (NT * 16) + t * 16 + m16] = f2b(acc[t][r]);
        }
    }
}

// ---------- fused: merged deg+fill edge pass || layer-1 GEMM (f32 A, unscaled) ----------
// 512-thread blocks. Same 1:2 interleave: gemm blocks = 8 waves x 16 rows = 128
// rows; edge blocks = 4096 edges. [R7: time-neutral vs 256t; kept for fewer blocks]
__global__ __launch_bounds__(512) void fg2_kernel(const float* __restrict__ A,
                                                  const unsigned short* __restrict__ Whi,
                                                  const unsigned short* __restrict__ Wlo,
                                                  unsigned short* __restrict__ C, int nrows,
                                                  int fbn,
                                                  const int* __restrict__ ei,
                                                  int* __restrict__ deg,
                                                  int* __restrict__ slots, int E) {
    const int bid = blockIdx.x;
    const int tid = threadIdx.x;
    const int trip = bid / 3, r = bid % 3;
    if (r == 1 && trip < fbn) {  // edge block: deg+fill merged, 8 edges/thread
        int base = (trip * 512 + tid) * 8;
        int dsts[8], srcs[8], ps[8];
#pragma unroll
        for (int k = 0; k < 8; ++k) {
            int e = base + k;
            dsts[k] = (e < E) ? ei[E + e] : -1;
            srcs[k] = (e < E) ? ei[e] : 0;
        }
#pragma unroll
        for (int k = 0; k < 8; ++k)
            if (dsts[k] >= 0) ps[k] = atomicAdd(&deg[dsts[k]], 1);
#pragma unroll
        for (int k = 0; k < 8; ++k)
            if (dsts[k] >= 0 && ps[k] < 64)  // cap 64 (P(deg>64) ~ 1e-24)
                __builtin_nontemporal_store(srcs[k], &slots[(size_t)dsts[k] * 64 + ps[k]]);
    } else {  // gemm block: 128 rows
        int gid = bid - min(trip, fbn) - ((r > 1 && trip < fbn) ? 1 : 0);
        const int wave = tid >> 6, lane = tid & 63;
        const int m16 = lane & 15, quad = lane >> 4;
        const int row_base = gid * 128 + wave * 16;
        int arow = row_base + m16;
        if (arow >= nrows) arow = nrows - 1;
        f32x4 acc[8] = {};
        gemm_acc_f32<8>(A, Whi, Wlo, arow, m16, quad, acc);
        gemm_store_plain<8>(C, row_base, m16, quad, acc, nrows);
    }
}

// ---------- scale hs in-place by rsqrt(deg+1) ----------
// [R8 post-mortem: folding this into layer-2's gather (per-src deg loads on the
// gather critical path) cost +17us vs this pass's 12us — keep it separate.]
__global__ __launch_bounds__(256) void scale_kernel(unsigned short* __restrict__ hs,
                                                    const int* __restrict__ deg, int n) {
    int idx = blockIdx.x * 256 + threadIdx.x;
    int node = idx >> 5;
    if (node >= n) return;
    int f = (idx & 31) * 4;
    float d = rsqrtf((float)deg[node] + 1.0f);
    ushort4 v = *reinterpret_cast<const ushort4*>(hs + (size_t)node * 128 + f);
    ushort4 o;
    o.x = f2b(b2f(v.x) * d);
    o.y = f2b(b2f(v.y) * d);
    o.z = f2b(b2f(v.z) * d);
    o.w = f2b(b2f(v.w) * d);
    *reinterpret_cast<ushort4*>(hs + (size_t)node * 128 + f) = o;
}

// ---------- pull 4 nodes (one wave) into rows [wave*4 .. wave*4+3] of the
// block's 32x128 swizzled LDS tile ----------
// EXACT R2/R5 inner loop (proven best codegen; R3/R8 both showed any extra op
// on this path regresses). Slot loads are LANE-MASKED (lane < deg): with avg
// deg~16, reads 1 of 4 cachelines of each 256B slot row instead of all 4.
// R8 gather form: lane = slot(0..3)*16 + chunk(0..15); per round slot s gathers
// 16B chunk of edge r*4+s. Row i stored at elem (chunk*8) ^ ((i&7)<<3)
// (byte ^ ((row&7)<<4)) so the MFMA-phase ds_read_b128 is bank-uniform.
static __device__ __forceinline__ void pull4_to_lds(const unsigned short* __restrict__ hs,
                                                    const int* __restrict__ slots,
                                                    const int* __restrict__ deg,
                                                    const float* __restrict__ bias,
                                                    unsigned short* __restrict__ ldsw,
                                                    int row_base, int wave, int lane, int n) {
    const int slot = lane >> 4, chunk = lane & 15;
    // prefetch setup for all 4 nodes (pipelines the deg/slots latencies)
    int dgs[4], idxs[4];
#pragma unroll
    for (int i = 0; i < 4; ++i) {
        int node = row_base + wave * 4 + i;
        dgs[i] = (node < n) ? deg[node] : 0;
    }
#pragma unroll
    for (int i = 0; i < 4; ++i) {
        int node = row_base + wave * 4 + i;
        // lane-masked: only lanes < deg load a slot entry (saves 3/4 of lines at deg~16)
        idxs[i] = (node < n && lane < min(dgs[i], 64)) ? slots[(size_t)node * 64 + lane] : 0;
    }
#pragma unroll
    for (int i = 0; i < 4; ++i) {
        const int node = row_base + wave * 4 + i;
        if (node >= n) continue;  // wave-uniform
        const int tr = wave * 4 + i;  // tile row
        const float d = rsqrtf((float)dgs[i] + 1.0f);
        const int m = min(dgs[i], 64);
        const int myidx = idxs[i];

        BU sv;
        sv.u = *reinterpret_cast<const u16x8*>(hs + (size_t)node * 128 + chunk * 8);

        float acc[8] = {};
        const int rounds = (m + 3) >> 2;
        int r = 0;
        for (; r + 4 <= rounds; r += 4) {
            int e0 = r * 4 + slot, e1 = e0 + 4, e2 = e0 + 8, e3 = e0 + 12;
            int s0 = __shfl(myidx, e0), s1 = __shfl(myidx, e1);
            int s2 = __shfl(myidx, e2), s3 = __shfl(myidx, e3);
            s0 = (unsigned)s0 < (unsigned)n ? s0 : 0;  // defensive (masked lanes hold 0)
            s1 = (unsigned)s1 < (unsigned)n ? s1 : 0;
            s2 = (unsigned)s2 < (unsigned)n ? s2 : 0;
            s3 = (unsigned)s3 < (unsigned)n ? s3 : 0;
            bool ok0 = e0 < m, ok1 = e1 < m, ok2 = e2 < m, ok3 = e3 < m;
            BU h0, h1, h2, h3;
            if (ok0) h0.u = *reinterpret_cast<const u16x8*>(hs + (size_t)s0 * 128 + chunk * 8);
            if (ok1) h1.u = *reinterpret_cast<const u16x8*>(hs + (size_t)s1 * 128 + chunk * 8);
            if (ok2) h2.u = *reinterpret_cast<const u16x8*>(hs + (size_t)s2 * 128 + chunk * 8);
            if (ok3) h3.u = *reinterpret_cast<const u16x8*>(hs + (size_t)s3 * 128 + chunk * 8);
            if (ok0) {
#pragma unroll
                for (int j = 0; j < 8; ++j) acc[j] += b2f(h0.u[j]);
            }
            if (ok1) {
#pragma unroll
                for (int j = 0; j < 8; ++j) acc[j] += b2f(h1.u[j]);
            }
            if (ok2) {
#pragma unroll
                for (int j = 0; j < 8; ++j) acc[j] += b2f(h2.u[j]);
            }
            if (ok3) {
#pragma unroll
                for (int j = 0; j < 8; ++j) acc[j] += b2f(h3.u[j]);
            }
        }
        for (; r < rounds; ++r) {
            int e0 = r * 4 + slot;
            int s0 = __shfl(myidx, e0);
            s0 = (unsigned)s0 < (unsigned)n ? s0 : 0;
            if (e0 < m) {
                BU h0;
                h0.u = *reinterpret_cast<const u16x8*>(hs + (size_t)s0 * 128 + chunk * 8);
#pragma unroll
                for (int j = 0; j < 8; ++j) acc[j] += b2f(h0.u[j]);
            }
        }
        // reduce across the 4 slots (lane bits 4,5)
#pragma unroll
        for (int j = 0; j < 8; ++j) {
            acc[j] += __shfl_xor(acc[j], 16);
            acc[j] += __shfl_xor(acc[j], 32);
        }
        if (slot == 0) {
            BU o;
#pragma unroll
            for (int j = 0; j < 8; ++j)
                o.u[j] = f2b(fmaxf((acc[j] + b2f(sv.u[j])) * d + bias[chunk * 8 + j], 0.f));
            *reinterpret_cast<u16x8*>(&ldsw[tr * 128 + ((chunk * 8) ^ ((tr & 7) << 3))]) = o.u;
        }
    }
}

// ---------- fused pull + GEMM (layers 2,3), 32-row tile, 512-thread blocks ----------
// 8 waves each pull 4 nodes, then each wave computes its 16 output cols for BOTH
// 16-row halves of the 32x128 @ 128x128 product (weights loaded once, used twice).
__global__ __launch_bounds__(512) void pg_kernel(const unsigned short* __restrict__ hs,
                                                 const int* __restrict__ slots,
                                                 const int* __restrict__ deg,
                                                 const float* __restrict__ bias,
                                                 const unsigned short* __restrict__ Whi,
                                                 const unsigned short* __restrict__ Wlo,
                                                 unsigned short* __restrict__ C, int n) {
    __shared__ unsigned short lds[32 * 128];  // 8 KiB swizzled tile
    const int tid = threadIdx.x;
    const int wave = tid >> 6, lane = tid & 63;
    const int row_base = blockIdx.x * 32;
    pull4_to_lds(hs, slots, deg, bias, lds, row_base, wave, lane, n);
    __syncthreads();
    const int m16 = lane & 15, quad = lane >> 4;
    f32x4 acc0 = {}, acc1 = {};
#pragma unroll
    for (int kb = 0; kb < 4; ++kb) {
        const int aoff = (quad * 8 + kb * 32) ^ ((m16 & 7) << 3);  // (16+m16)&7 == m16&7
        BU a0, a1;
        a0.u = *reinterpret_cast<const u16x8*>(&lds[m16 * 128 + aoff]);
        a1.u = *reinterpret_cast<const u16x8*>(&lds[(16 + m16) * 128 + aoff]);
        int col = wave * 16 + m16;
        size_t woff = (size_t)col * 128 + quad * 8 + kb * 32;
        BU bh, bl;
        bh.u = *reinterpret_cast<const u16x8*>(Whi + woff);
        bl.u = *reinterpret_cast<const u16x8*>(Wlo + woff);
        acc0 = __builtin_amdgcn_mfma_f32_16x16x32_bf16(a0.b, bh.b, acc0, 0, 0, 0);
        acc0 = __builtin_amdgcn_mfma_f32_16x16x32_bf16(a0.b, bl.b, acc0, 0, 0, 0);
        acc1 = __builtin_amdgcn_mfma_f32_16x16x32_bf16(a1.b, bh.b, acc1, 0, 0, 0);
        acc1 = __builtin_amdgcn_mfma_f32_16x16x32_bf16(a1.b, bl.b, acc1, 0, 0, 0);
    }
#pragma unroll
    for (int r = 0; r < 4; ++r) {
        int row0 = row_base + quad * 4 + r;
        int row1 = row_base + 16 + quad * 4 + r;
        if (row0 < n) {
            float d = rsqrtf((float)deg[row0] + 1.0f);
            C[(size_t)row0 * 128 + wave * 16 + m16] = f2b(acc0[r] * d);
        }
        if (row1 < n) {
            float d = rsqrtf((float)deg[row1] + 1.0f);
            C[(size_t)row1 * 128 + wave * 16 + m16] = f2b(acc1[r] * d);
        }
    }
}

// ---------- fused pull + heads GEMM (12 col-tiles over 8 waves) + reduce -> out[N,3] ----------
// 32-row tile. Every wave computes pos-head tile 'wave' (cols wave*16..+15) for
// both row halves; waves 0-3 additionally compute the time-head tile
// (cols 128+wave*16..) for both halves.
__global__ __launch_bounds__(512) void pg_heads_kernel(
    const unsigned short* __restrict__ hs, const int* __restrict__ slots,
    const int* __restrict__ deg, const float* __restrict__ bias,
    const unsigned short* __restrict__ Whi, const unsigned short* __restrict__ Wlo,
    const float* __restrict__ bcat, const float* __restrict__ Wp2,
    const float* __restrict__ bp2, const float* __restrict__ Wt2,
    const float* __restrict__ bt2, float* __restrict__ out, int n) {
    __shared__ unsigned short lds[32 * 128];
    __shared__ float part[8][32][3];
    const int tid = threadIdx.x;
    const int wave = tid >> 6, lane = tid & 63;
    const int row_base = blockIdx.x * 32;
    pull4_to_lds(hs, slots, deg, bias, lds, row_base, wave, lane, n);
    __syncthreads();
    const int m16 = lane & 15, quad = lane >> 4;
    f32x4 acc0a = {}, acc0b = {}, acc1a = {}, acc1b = {};
#pragma unroll
    for (int kb = 0; kb < 4; ++kb) {
        const int aoff = (quad * 8 + kb * 32) ^ ((m16 & 7) << 3);
        BU a0, a1;
        a0.u = *reinterpret_cast<const u16x8*>(&lds[m16 * 128 + aoff]);
        a1.u = *reinterpret_cast<const u16x8*>(&lds[(16 + m16) * 128 + aoff]);
        {
            int col = wave * 16 + m16;
            size_t woff = (size_t)col * 128 + quad * 8 + kb * 32;
            BU bh, bl;
            bh.u = *reinterpret_cast<const u16x8*>(Whi + woff);
            bl.u = *reinterpret_cast<const u16x8*>(Wlo + woff);
            acc0a = __builtin_amdgcn_mfma_f32_16x16x32_bf16(a0.b, bh.b, acc0a, 0, 0, 0);
            acc0a = __builtin_amdgcn_mfma_f32_16x16x32_bf16(a0.b, bl.b, acc0a, 0, 0, 0);
            acc0b = __builtin_amdgcn_mfma_f32_16x16x32_bf16(a1.b, bh.b, acc0b, 0, 0, 0);
            acc0b = __builtin_amdgcn_mfma_f32_16x16x32_bf16(a1.b, bl.b, acc0b, 0, 0, 0);
        }
        if (wave < 4) {
            int col = 128 + wave * 16 + m16;
            size_t woff = (size_t)col * 128 + quad * 8 + kb * 32;
            BU bh, bl;
            bh.u = *reinterpret_cast<const u16x8*>(Whi + woff);
            bl.u = *reinterpret_cast<const u16x8*>(Wlo + woff);
            acc1a = __builtin_amdgcn_mfma_f32_16x16x32_bf16(a0.b, bh.b, acc1a, 0, 0, 0);
            acc1a = __builtin_amdgcn_mfma_f32_16x16x32_bf16(a0.b, bl.b, acc1a, 0, 0, 0);
            acc1b = __builtin_amdgcn_mfma_f32_16x16x32_bf16(a1.b, bh.b, acc1b, 0, 0, 0);
            acc1b = __builtin_amdgcn_mfma_f32_16x16x32_bf16(a1.b, bl.b, acc1b, 0, 0, 0);
        }
    }
    // per-wave partial head reduction over its col tiles (both row halves)
#pragma unroll
    for (int r = 0; r < 4; ++r) {
        float p0a, p1a, tta = 0.f, p0b, p1b, ttb = 0.f;
        {
            int c = wave * 16 + m16;  // pos-head col (<128)
            float w0 = Wp2[c * 2 + 0], w1 = Wp2[c * 2 + 1], bc = bcat[c];
            float va = fmaxf(acc0a[r] + bc, 0.f);
            float vb = fmaxf(acc0b[r] + bc, 0.f);
            p0a = va * w0; p1a = va * w1;
            p0b = vb * w0; p1b = vb * w1;
        }
        if (wave < 4) {
            int c = 128 + wave * 16 + m16;  // time-head col
            float wt = Wt2[c - 128], bc = bcat[c];
            tta = fmaxf(acc1a[r] + bc, 0.f) * wt;
            ttb = fmaxf(acc1b[r] + bc, 0.f) * wt;
        }
#pragma unroll
        for (int mask = 1; mask < 16; mask <<= 1) {
            p0a += __shfl_xor(p0a, mask);
            p1a += __shfl_xor(p1a, mask);
            tta += __shfl_xor(tta, mask);
            p0b += __shfl_xor(p0b, mask);
            p1b += __shfl_xor(p1b, mask);
            ttb += __shfl_xor(ttb, mask);
        }
        if (m16 == 0) {
            int trow = quad * 4 + r;
            part[wave][trow][0] = p0a;
            part[wave][trow][1] = p1a;
            part[wave][trow][2] = tta;
            part[wave][16 + trow][0] = p0b;
            part[wave][16 + trow][1] = p1b;
            part[wave][16 + trow][2] = ttb;
        }
    }
    __syncthreads();
    if (tid < 96) {
        int trow = tid / 3, c = tid - trow * 3;
        float s = 0.f;
#pragma unroll
        for (int w = 0; w < 8; ++w) s += part[w][trow][c];
        int row = row_base + trow;
        if (row < n) {
            float b = (c == 0) ? bp2[0] : (c == 1) ? bp2[1] : bt2[0];
            out[(size_t)row * 3 + c] = s + b;
        }
    }
}

// ---------- launcher ----------
extern "C" void kernel_launch(void* const* d_in, const int* in_sizes, int n_in,
                              void* d_out, int out_size, void* d_ws, size_t ws_size,
                              hipStream_t stream) {
    const int N = in_sizes[0] / 128;
    const int E = in_sizes[1] / 2;

    const float* x   = (const float*)d_in[0];
    const int* ei    = (const int*)d_in[1];
    const float* W1  = (const float*)d_in[2];
    const float* b1  = (const float*)d_in[3];
    const float* W2  = (const float*)d_in[4];
    const float* b2  = (const float*)d_in[5];
    const float* W3  = (const float*)d_in[6];
    const float* b3  = (const float*)d_in[7];
    const float* Wp1 = (const float*)d_in[8];
    const float* bp1 = (const float*)d_in[9];
    const float* Wp2 = (const float*)d_in[10];
    const float* bp2 = (const float*)d_in[11];
    const float* Wt1 = (const float*)d_in[12];
    const float* bt1 = (const float*)d_in[13];
    const float* Wt2 = (const float*)d_in[14];
    const float* bt2 = (const float*)d_in[15];
    float* out = (float*)d_out;

    char* ws = (char*)d_ws;
    size_t off = 0;
    auto alloc = [&](size_t bytes) {
        void* p = ws + off;
        off += (bytes + 255) & ~(size_t)255;
        return p;
    };
    int* deg        = (int*)alloc((size_t)N * 4);
    int* slots      = (int*)alloc((size_t)N * 64 * 4);
    unsigned short* W1hi = (unsigned short*)alloc(16384 * 2);
    unsigned short* W1lo = (unsigned short*)alloc(16384 * 2);
    unsigned short* W2hi = (unsigned short*)alloc(16384 * 2);
    unsigned short* W2lo = (unsigned short*)alloc(16384 * 2);
    unsigned short* W3hi = (unsigned short*)alloc(16384 * 2);
    unsigned short* W3lo = (unsigned short*)alloc(16384 * 2);
    unsigned short* Wchi = (unsigned short*)alloc(192 * 128 * 2);
    unsigned short* Wclo = (unsigned short*)alloc(192 * 128 * 2);
    float* bcat          = (float*)alloc(192 * 4);
    unsigned short* hsA  = (unsigned short*)alloc((size_t)N * 128 * 2);
    unsigned short* hsB  = (unsigned short*)alloc((size_t)N * 128 * 2);

    hipMemsetAsync(deg, 0, (size_t)N * 4, stream);

    // weight split + bcat (must finish before fg2's gemm reads W1hi/lo)
    wsplit_kernel<<<289, 256, 0, stream>>>(W1, W2, W3, Wp1, Wt1,
                                           W1hi, W1lo, W2hi, W2lo, W3hi, W3lo,
                                           Wchi, Wclo, bp1, bt1, bcat);

    const int gb128 = (N + 127) / 128;
    const int gb32 = (N + 31) / 32;
    const int fbn = ((E + 7) / 8 + 511) / 512;

    // edge pass (deg+fill merged) || layer-1 GEMM (unscaled), 1:2 interleave
    fg2_kernel<<<gb128 + fbn, 512, 0, stream>>>(x, W1hi, W1lo, hsA, N, fbn, ei, deg, slots, E);
    // hsA *= rsqrt(deg+1) in-place (pre-scale for the first gather)
    scale_kernel<<<(N * 32 + 255) / 256, 256, 0, stream>>>(hsA, deg, N);

    // layer 2: gather hsA -> h1 rows -> @W2 -> pre-scaled hsB
    pg_kernel<<<gb32, 512, 0, stream>>>(hsA, slots, deg, b1, W2hi, W2lo, hsB, N);
    // layer 3: gather hsB -> h2 rows -> @W3 -> pre-scaled hsA
    pg_kernel<<<gb32, 512, 0, stream>>>(hsB, slots, deg, b2, W3hi, W3lo, hsA, N);
    // heads: gather hsA -> h3 rows -> @[Wp1|Wt1] -> fused head reduce -> out
    pg_heads_kernel<<<gb32, 512, 0, stream>>>(hsA, slots, deg, b3, Wchi, Wclo,
                                              bcat, Wp2, bp2, Wt2, bt2, out, N);
}